// Round 3
// baseline (114.641 us; speedup 1.0000x reference)
//
#include <hip/hip_runtime.h>
#include <math.h>

#define N_NODES 2000
#define E_DIM   128
#define QKV_W   384
#define LDA     36   // A-tile leading dim pad
#define GEMM_BLOCKS 189

// ---------------------------------------------------------------------------
// Kernel 1: fused prep + qkv (+16 tail blocks transpose out_w -> out_wT).
// ---------------------------------------------------------------------------
__global__ __launch_bounds__(256) void prep_qkv_kernel(
    const float* __restrict__ x, const float* __restrict__ coords9,
    const float* __restrict__ ps, const float* __restrict__ pe_w,
    const float* __restrict__ pe_b, const float* __restrict__ pe_g,
    const float* __restrict__ pe_bt, const float* __restrict__ in_w,
    const float* __restrict__ in_b, const float* __restrict__ out_w,
    float4* __restrict__ cw, float* __restrict__ qkv,
    float* __restrict__ out_wT)
{
    __shared__ __align__(16) float As[E_DIM * LDA]; // As[c][r]
    int tid = threadIdx.x;

    // ---- tail blocks: one-time 128x128 transpose of out_w (64 KB)
    if (blockIdx.x >= GEMM_BLOCKS) {
        int bid2 = blockIdx.x - GEMM_BLOCKS;       // 0..15
        int g2 = tid >> 5, lane2 = tid & 31;
        int k = bid2 * 8 + g2;
        #pragma unroll
        for (int m = 0; m < 4; ++m) {
            int e = lane2 + 32 * m;
            out_wT[k * 128 + e] = out_w[e * 128 + k];
        }
        return;
    }

    int rt = blockIdx.x / 3, ct = blockIdx.x % 3;
    int rbase = rt * 32, cbase = ct * 128;
    int g = tid >> 5, lane = tid & 31;

    #pragma unroll
    for (int rr = 0; rr < 4; ++rr) {
        int rl = rr * 8 + g;
        int row = rbase + rl;
        bool vr = (row < N_NODES);
        float cx = 0.f, cy = 0.f, cz = 0.f;
        if (vr) {
            const float* c9 = coords9 + row * 9;
            cx = (c9[0] + c9[3] + c9[6]) * (1.0f / 3.0f);
            cy = (c9[1] + c9[4] + c9[7]) * (1.0f / 3.0f);
            cz = (c9[2] + c9[5] + c9[8]) * (1.0f / 3.0f);
        }
        if (ct == 0 && vr && lane == 0) {
            float4 c4; c4.x = cx; c4.y = cy; c4.z = cz; c4.w = 0.f;
            cw[row] = c4;
        }

        #pragma unroll
        for (int k = 0; k < 3; ++k) {
            int c = lane + 32 * k;
            float v = vr ? (x[row * E_DIM + c] + ps[c]) : 0.f;
            As[c * LDA + rl] = v;
        }

        int j = lane;
        float h = cx * pe_w[j] + cy * pe_w[32 + j] + cz * pe_w[64 + j] + pe_b[j];
        float ge = 0.5f * h * (1.0f + erff(h * 0.7071067811865476f)); // exact GELU
        float s = ge;
        #pragma unroll
        for (int m = 16; m >= 1; m >>= 1) s += __shfl_xor(s, m);
        float mu = s * (1.0f / 32.0f);
        float d = ge - mu;
        float v2 = d * d;
        #pragma unroll
        for (int m = 16; m >= 1; m >>= 1) v2 += __shfl_xor(v2, m);
        float var = v2 * (1.0f / 32.0f);
        float y = d * (1.0f / sqrtf(var + 1e-5f)) * pe_g[j] + pe_bt[j];
        As[(96 + j) * LDA + rl] = vr ? y : 0.f;
    }
    __syncthreads();

    int cg = tid & 31, rg = tid >> 5;
    int c0 = cbase + cg * 4, r0 = rg * 4;
    float acc[4][4];
    #pragma unroll
    for (int i = 0; i < 4; ++i)
        #pragma unroll
        for (int jj = 0; jj < 4; ++jj) acc[i][jj] = 0.f;

    for (int k0 = 0; k0 < 128; k0 += 4) {
        float4 a0 = *(const float4*)&As[(k0 + 0) * LDA + r0];
        float4 a1 = *(const float4*)&As[(k0 + 1) * LDA + r0];
        float4 a2 = *(const float4*)&As[(k0 + 2) * LDA + r0];
        float4 a3 = *(const float4*)&As[(k0 + 3) * LDA + r0];
        #pragma unroll
        for (int ci = 0; ci < 4; ++ci) {
            float4 b = *(const float4*)&in_w[(c0 + ci) * E_DIM + k0];
            acc[0][ci] += a0.x * b.x + a1.x * b.y + a2.x * b.z + a3.x * b.w;
            acc[1][ci] += a0.y * b.x + a1.y * b.y + a2.y * b.z + a3.y * b.w;
            acc[2][ci] += a0.z * b.x + a1.z * b.y + a2.z * b.z + a3.z * b.w;
            acc[3][ci] += a0.w * b.x + a1.w * b.y + a2.w * b.z + a3.w * b.w;
        }
    }

    #pragma unroll
    for (int ri = 0; ri < 4; ++ri) {
        int row = rbase + r0 + ri;
        if (row < N_NODES) {
            float4 o4;
            o4.x = acc[ri][0] + in_b[c0 + 0];
            o4.y = acc[ri][1] + in_b[c0 + 1];
            o4.z = acc[ri][2] + in_b[c0 + 2];
            o4.w = acc[ri][3] + in_b[c0 + 3];
            *(float4*)&qkv[row * QKV_W + c0] = o4;
        }
    }
}

// ---------------------------------------------------------------------------
// Kernel 2: fused attn + out-proj. R8: 4-way per-wave private histograms
// (no inter-wave atomic contention); PV and out-proj run split-k on all 256
// threads (halves the two longest L2-latency chains) with 2-way LDS combine.
// ---------------------------------------------------------------------------
__device__ __forceinline__ float sanitize(float v)
{
    v = (v == v) ? v : 0.f;
    return fminf(fmaxf(v, -1e4f), 1e4f);
}

__global__ __launch_bounds__(256) void attn_proj_kernel(
    const float4* __restrict__ cw, const float* __restrict__ qkv,
    const float* __restrict__ out_wT, const float* __restrict__ out_b,
    float* __restrict__ out)
{
    __shared__ unsigned int hist[1024];  // 4 per-wave sub-histograms
    __shared__ float wMin[4], wMax[4];
    __shared__ int sh_b, sh_nless, sh_sel, sh_eq;
    __shared__ int waveSum[4];
    __shared__ int topk[32];
    __shared__ int eqIdx[256];
    __shared__ unsigned int eqKey[256];
    __shared__ __align__(16) float qs[128];
    __shared__ float pr[256];
    __shared__ __align__(16) float os[128];
    __shared__ float part[256];

    int tid = threadIdx.x;
    int row = blockIdx.x;
    int lane = tid & 63, wid = tid >> 6;

    float4 ci = cw[row];
    float cix = ci.x, ciy = ci.y, ciz = ci.z;
    unsigned int kbits[8];
    int bins[8];
    bool valid[8];
    float lmin = __int_as_float(0x7f800000);
    float lmax = __int_as_float(0xff800000);
    {
        #pragma clang fp contract(off)  // match reference bit pattern exactly
        #pragma unroll
        for (int l = 0; l < 8; ++l) {
            int j = tid + 256 * l;
            valid[l] = (j < N_NODES);
            float key = __int_as_float(0x7f800000);
            if (valid[l]) {
                float4 cj = cw[j];
                float dx = cix - cj.x;
                float dy = ciy - cj.y;
                float dz = ciz - cj.z;
                float a = dx * dx;
                float b = dy * dy;
                float c = dz * dz;
                float d2 = ((a + b) + c) + 1e-20f;
                key = sqrtf(d2);
                lmin = fminf(lmin, key);
                lmax = fmaxf(lmax, key);
            }
            kbits[l] = __float_as_uint(key);
        }
    }

    // ---- block min/max (wave reduce -> LDS -> all threads reduce 4)
    #pragma unroll
    for (int m = 32; m >= 1; m >>= 1) {
        lmin = fminf(lmin, __shfl_xor(lmin, m));
        lmax = fmaxf(lmax, __shfl_xor(lmax, m));
    }
    if (lane == 0) { wMin[wid] = lmin; wMax[wid] = lmax; }
    hist[tid] = 0u;
    hist[tid + 256] = 0u;
    hist[tid + 512] = 0u;
    hist[tid + 768] = 0u;
    if (tid == 0) { sh_sel = 0; sh_eq = 0; }
    __syncthreads();
    // all threads compute lo/scale redundantly (saves a barrier)
    float lo = fminf(fminf(wMin[0], wMin[1]), fminf(wMin[2], wMin[3]));
    float hi = fmaxf(fmaxf(wMax[0], wMax[1]), fmaxf(wMax[2], wMax[3]));
    float scale = 255.0f / fmaxf(hi - lo, 1e-30f);

    // ---- linear-value histogram; per-wave private sub-histograms
    unsigned int hsel = (unsigned int)wid << 8;
    #pragma unroll
    for (int l = 0; l < 8; ++l) {
        int bin = 255;
        if (valid[l]) {
            float key = __uint_as_float(kbits[l]);
            bin = (int)((key - lo) * scale);
            bin = min(max(bin, 0), 255);
            atomicAdd(&hist[hsel + bin], 1u);
        }
        bins[l] = bin;
    }
    __syncthreads();

    // ---- inclusive prefix scan over 256 bins; find boundary bin
    int h = (int)(hist[tid] + hist[tid + 256] + hist[tid + 512] + hist[tid + 768]);
    int incl = h;
    #pragma unroll
    for (int dd = 1; dd < 64; dd <<= 1) {
        int u = __shfl_up(incl, dd);
        if (lane >= dd) incl += u;
    }
    if (lane == 63) waveSum[wid] = incl;
    __syncthreads();
    int off = 0;
    for (int w = 0; w < wid; ++w) off += waveSum[w];
    int cum = incl + off;
    if (cum >= 32 && (cum - h) < 32) {  // unique crossing bin (h>0 there)
        sh_b = tid;
        sh_nless = cum - h;
    }
    __syncthreads();

    int b = sh_b;
    int req = 32 - sh_nless;

    // ---- collect (bins from registers)
    #pragma unroll
    for (int l = 0; l < 8; ++l) {
        if (valid[l]) {
            int bin = bins[l];
            int j = tid + 256 * l;
            if (bin < b) {
                int p = atomicAdd(&sh_sel, 1);
                topk[p] = j;
            } else if (bin == b) {
                int e = atomicAdd(&sh_eq, 1);
                if (e < 256) { eqIdx[e] = j; eqKey[e] = kbits[l]; }
            }
        }
    }
    if (tid < 128) qs[tid] = qkv[row * QKV_W + tid];  // stage q meanwhile
    __syncthreads();

    // ---- boundary bin: exact rank on (uint32 key, index), lower index wins
    int eq = min(sh_eq, 256);
    if (tid < eq) {
        int myIdx = eqIdx[tid];
        unsigned int myKey = eqKey[tid];
        int rank = 0;
        for (int u = 0; u < eq; ++u) {
            unsigned int ku = eqKey[u];
            rank += (ku < myKey || (ku == myKey && eqIdx[u] < myIdx)) ? 1 : 0;
        }
        if (rank < req) {
            int p = atomicAdd(&sh_sel, 1);
            topk[p] = myIdx;
        }
    }
    __syncthreads();

    // ---- scores + softmax: thread = (head hh, slot j)
    {
        int hh = tid >> 5, j = tid & 31;
        int jj = topk[j];
        const float4* kp = (const float4*)&qkv[jj * QKV_W + 128 + hh * 16];
        const float4* qp = (const float4*)&qs[hh * 16];
        float s = 0.f;
        #pragma unroll
        for (int i = 0; i < 4; ++i) {
            float4 kv = kp[i], qv = qp[i];
            s += qv.x * kv.x + qv.y * kv.y + qv.z * kv.z + qv.w * kv.w;
        }
        s *= 0.25f;
        float m = s;
        #pragma unroll
        for (int msk = 16; msk >= 1; msk >>= 1) m = fmaxf(m, __shfl_xor(m, msk));
        float p = expf(s - m);
        float su = p;
        #pragma unroll
        for (int msk = 16; msk >= 1; msk >>= 1) su += __shfl_xor(su, msk);
        pr[tid] = p / su;
    }
    __syncthreads();

    // ---- o = probs @ v : split-k on 256 threads (16 gathers/thread)
    {
        int e = tid & 127, half = tid >> 7;
        int hh = e >> 4;
        float acc = 0.f;
        #pragma unroll
        for (int j = 0; j < 16; ++j) {
            int js = half * 16 + j;
            int jj = topk[js];
            acc += pr[hh * 32 + js] * qkv[jj * QKV_W + 256 + e];
        }
        part[tid] = acc;
    }
    __syncthreads();
    if (tid < 128) os[tid] = part[tid] + part[tid + 128];
    __syncthreads();

    // ---- out-projection: split-k on 256 threads (64 loads/thread)
    {
        int e = tid & 127, half = tid >> 7;
        const float* wp = out_wT + half * 64 * 128 + e;
        const float* op = os + half * 64;
        float a = 0.f;
        #pragma unroll
        for (int k = 0; k < 64; k += 4) {
            a += op[k + 0] * wp[(k + 0) * 128]
               + op[k + 1] * wp[(k + 1) * 128]
               + op[k + 2] * wp[(k + 2) * 128]
               + op[k + 3] * wp[(k + 3) * 128];
        }
        part[tid] = a;
    }
    __syncthreads();
    if (tid < 128)
        out[row * E_DIM + tid] = sanitize(part[tid] + part[tid + 128] + out_b[tid]);
}

// ---------------------------------------------------------------------------
extern "C" void kernel_launch(void* const* d_in, const int* in_sizes, int n_in,
                              void* d_out, int out_size, void* d_ws, size_t ws_size,
                              hipStream_t stream)
{
    const float* x      = (const float*)d_in[0];
    const float* coords = (const float*)d_in[1];
    const float* ps     = (const float*)d_in[2];
    const float* pe_w   = (const float*)d_in[3];
    const float* pe_b   = (const float*)d_in[4];
    const float* pe_g   = (const float*)d_in[5];
    const float* pe_bt  = (const float*)d_in[6];
    const float* in_w   = (const float*)d_in[7];
    const float* in_b   = (const float*)d_in[8];
    const float* out_w  = (const float*)d_in[9];
    const float* out_b  = (const float*)d_in[10];
    float* out = (float*)d_out;

    float* ws    = (float*)d_ws;
    float4* cw   = (float4*)ws;          // 2048 float4 = 8192 floats
    float* qkvb  = ws + 8192;            // 2000*384 = 768000
    float* owT   = ws + 8192 + 768000;   // 128*128 = 16384

    prep_qkv_kernel<<<GEMM_BLOCKS + 16, 256, 0, stream>>>(
        x, coords, ps, pe_w, pe_b, pe_g, pe_bt, in_w, in_b, out_w,
        cw, qkvb, owT);
    attn_proj_kernel<<<2000, 256, 0, stream>>>(cw, qkvb, owT, out_b, out);
}

// Round 4
// 114.248 us; speedup vs baseline: 1.0034x; 1.0034x over previous
//
#include <hip/hip_runtime.h>
#include <math.h>

#define N_NODES 2000
#define E_DIM   128
#define QKV_W   384
#define LDA     36   // A-tile leading dim pad
#define GEMM_BLOCKS 189

// ---------------------------------------------------------------------------
// Kernel 1: fused prep + qkv (+16 tail blocks transpose out_w -> out_wT).
// ---------------------------------------------------------------------------
__global__ __launch_bounds__(256) void prep_qkv_kernel(
    const float* __restrict__ x, const float* __restrict__ coords9,
    const float* __restrict__ ps, const float* __restrict__ pe_w,
    const float* __restrict__ pe_b, const float* __restrict__ pe_g,
    const float* __restrict__ pe_bt, const float* __restrict__ in_w,
    const float* __restrict__ in_b, const float* __restrict__ out_w,
    float4* __restrict__ cw, float* __restrict__ qkv,
    float* __restrict__ out_wT)
{
    __shared__ __align__(16) float As[E_DIM * LDA]; // As[c][r]
    int tid = threadIdx.x;

    // ---- tail blocks: one-time 128x128 transpose of out_w (64 KB)
    if (blockIdx.x >= GEMM_BLOCKS) {
        int bid2 = blockIdx.x - GEMM_BLOCKS;       // 0..15
        int g2 = tid >> 5, lane2 = tid & 31;
        int k = bid2 * 8 + g2;
        #pragma unroll
        for (int m = 0; m < 4; ++m) {
            int e = lane2 + 32 * m;
            out_wT[k * 128 + e] = out_w[e * 128 + k];
        }
        return;
    }

    int rt = blockIdx.x / 3, ct = blockIdx.x % 3;
    int rbase = rt * 32, cbase = ct * 128;
    int g = tid >> 5, lane = tid & 31;

    #pragma unroll
    for (int rr = 0; rr < 4; ++rr) {
        int rl = rr * 8 + g;
        int row = rbase + rl;
        bool vr = (row < N_NODES);
        float cx = 0.f, cy = 0.f, cz = 0.f;
        if (vr) {
            const float* c9 = coords9 + row * 9;
            cx = (c9[0] + c9[3] + c9[6]) * (1.0f / 3.0f);
            cy = (c9[1] + c9[4] + c9[7]) * (1.0f / 3.0f);
            cz = (c9[2] + c9[5] + c9[8]) * (1.0f / 3.0f);
        }
        if (ct == 0 && vr && lane == 0) {
            float4 c4; c4.x = cx; c4.y = cy; c4.z = cz; c4.w = 0.f;
            cw[row] = c4;
        }

        #pragma unroll
        for (int k = 0; k < 3; ++k) {
            int c = lane + 32 * k;
            float v = vr ? (x[row * E_DIM + c] + ps[c]) : 0.f;
            As[c * LDA + rl] = v;
        }

        int j = lane;
        float h = cx * pe_w[j] + cy * pe_w[32 + j] + cz * pe_w[64 + j] + pe_b[j];
        float ge = 0.5f * h * (1.0f + erff(h * 0.7071067811865476f)); // exact GELU
        float s = ge;
        #pragma unroll
        for (int m = 16; m >= 1; m >>= 1) s += __shfl_xor(s, m);
        float mu = s * (1.0f / 32.0f);
        float d = ge - mu;
        float v2 = d * d;
        #pragma unroll
        for (int m = 16; m >= 1; m >>= 1) v2 += __shfl_xor(v2, m);
        float var = v2 * (1.0f / 32.0f);
        float y = d * (1.0f / sqrtf(var + 1e-5f)) * pe_g[j] + pe_bt[j];
        As[(96 + j) * LDA + rl] = vr ? y : 0.f;
    }
    __syncthreads();

    int cg = tid & 31, rg = tid >> 5;
    int c0 = cbase + cg * 4, r0 = rg * 4;
    float acc[4][4];
    #pragma unroll
    for (int i = 0; i < 4; ++i)
        #pragma unroll
        for (int jj = 0; jj < 4; ++jj) acc[i][jj] = 0.f;

    for (int k0 = 0; k0 < 128; k0 += 4) {
        float4 a0 = *(const float4*)&As[(k0 + 0) * LDA + r0];
        float4 a1 = *(const float4*)&As[(k0 + 1) * LDA + r0];
        float4 a2 = *(const float4*)&As[(k0 + 2) * LDA + r0];
        float4 a3 = *(const float4*)&As[(k0 + 3) * LDA + r0];
        #pragma unroll
        for (int ci = 0; ci < 4; ++ci) {
            float4 b = *(const float4*)&in_w[(c0 + ci) * E_DIM + k0];
            acc[0][ci] += a0.x * b.x + a1.x * b.y + a2.x * b.z + a3.x * b.w;
            acc[1][ci] += a0.y * b.x + a1.y * b.y + a2.y * b.z + a3.y * b.w;
            acc[2][ci] += a0.z * b.x + a1.z * b.y + a2.z * b.z + a3.z * b.w;
            acc[3][ci] += a0.w * b.x + a1.w * b.y + a2.w * b.z + a3.w * b.w;
        }
    }

    #pragma unroll
    for (int ri = 0; ri < 4; ++ri) {
        int row = rbase + r0 + ri;
        if (row < N_NODES) {
            float4 o4;
            o4.x = acc[ri][0] + in_b[c0 + 0];
            o4.y = acc[ri][1] + in_b[c0 + 1];
            o4.z = acc[ri][2] + in_b[c0 + 2];
            o4.w = acc[ri][3] + in_b[c0 + 3];
            *(float4*)&qkv[row * QKV_W + c0] = o4;
        }
    }
}

// ---------------------------------------------------------------------------
// Kernel 2: fused attn + out-proj, TWO rows per block (R9). Per-block fixed
// traffic (cw 32KB distance reads, out_wT 64KB proj reads) amortized over 2
// rows; selection runs both rows concurrently (dual hist/scan, per-row
// collect+rank identical to single-row logic -> bit-identical per row).
// ---------------------------------------------------------------------------
__device__ __forceinline__ float sanitize(float v)
{
    v = (v == v) ? v : 0.f;
    return fminf(fmaxf(v, -1e4f), 1e4f);
}

__global__ __launch_bounds__(256) void attn_proj_kernel(
    const float4* __restrict__ cw, const float* __restrict__ qkv,
    const float* __restrict__ out_wT, const float* __restrict__ out_b,
    float* __restrict__ out)
{
    __shared__ unsigned int hist[1024];   // [row][sub][256]
    __shared__ float wMinA[4], wMaxA[4], wMinB[4], wMaxB[4];
    __shared__ int sh_b[2], sh_nless[2], sh_sel[2], sh_eq[2];
    __shared__ int waveSumA[4], waveSumB[4];
    __shared__ int topkA[32], topkB[32];
    __shared__ int eqIdxA[256], eqIdxB[256];
    __shared__ unsigned int eqKeyA[256], eqKeyB[256];
    __shared__ __align__(16) float qsA[128], qsB[128];
    __shared__ float prA[256], prB[256];
    __shared__ __align__(16) float osA[128], osB[128];

    int tid = threadIdx.x;
    int rA = blockIdx.x * 2, rB = rA + 1;
    int lane = tid & 63, wid = tid >> 6;

    float4 cAv = cw[rA], cBv = cw[rB];
    unsigned int kbA[8], kbB[8];
    int binsA[8], binsB[8];
    bool valid[8];
    float lminA = __int_as_float(0x7f800000), lmaxA = __int_as_float(0xff800000);
    float lminB = __int_as_float(0x7f800000), lmaxB = __int_as_float(0xff800000);
    {
        #pragma clang fp contract(off)  // match reference bit pattern exactly
        #pragma unroll
        for (int l = 0; l < 8; ++l) {
            int j = tid + 256 * l;
            valid[l] = (j < N_NODES);
            float keyA = __int_as_float(0x7f800000);
            float keyB = __int_as_float(0x7f800000);
            if (valid[l]) {
                float4 cj = cw[j];   // one load serves BOTH rows
                float dxA = cAv.x - cj.x, dyA = cAv.y - cj.y, dzA = cAv.z - cj.z;
                float aA = dxA * dxA, bA = dyA * dyA, cA_ = dzA * dzA;
                float d2A = ((aA + bA) + cA_) + 1e-20f;
                keyA = sqrtf(d2A);
                lminA = fminf(lminA, keyA);
                lmaxA = fmaxf(lmaxA, keyA);
                float dxB = cBv.x - cj.x, dyB = cBv.y - cj.y, dzB = cBv.z - cj.z;
                float aB = dxB * dxB, bB = dyB * dyB, cB_ = dzB * dzB;
                float d2B = ((aB + bB) + cB_) + 1e-20f;
                keyB = sqrtf(d2B);
                lminB = fminf(lminB, keyB);
                lmaxB = fmaxf(lmaxB, keyB);
            }
            kbA[l] = __float_as_uint(keyA);
            kbB[l] = __float_as_uint(keyB);
        }
    }

    // ---- block min/max for both rows
    #pragma unroll
    for (int m = 32; m >= 1; m >>= 1) {
        lminA = fminf(lminA, __shfl_xor(lminA, m));
        lmaxA = fmaxf(lmaxA, __shfl_xor(lmaxA, m));
        lminB = fminf(lminB, __shfl_xor(lminB, m));
        lmaxB = fmaxf(lmaxB, __shfl_xor(lmaxB, m));
    }
    if (lane == 0) {
        wMinA[wid] = lminA; wMaxA[wid] = lmaxA;
        wMinB[wid] = lminB; wMaxB[wid] = lmaxB;
    }
    hist[tid] = 0u; hist[tid + 256] = 0u; hist[tid + 512] = 0u; hist[tid + 768] = 0u;
    if (tid == 0) { sh_sel[0] = 0; sh_sel[1] = 0; sh_eq[0] = 0; sh_eq[1] = 0; }
    __syncthreads();
    float loA = fminf(fminf(wMinA[0], wMinA[1]), fminf(wMinA[2], wMinA[3]));
    float hiA = fmaxf(fmaxf(wMaxA[0], wMaxA[1]), fmaxf(wMaxA[2], wMaxA[3]));
    float scaleA = 255.0f / fmaxf(hiA - loA, 1e-30f);
    float loB = fminf(fminf(wMinB[0], wMinB[1]), fminf(wMinB[2], wMinB[3]));
    float hiB = fmaxf(fmaxf(wMaxB[0], wMaxB[1]), fmaxf(wMaxB[2], wMaxB[3]));
    float scaleB = 255.0f / fmaxf(hiB - loB, 1e-30f);

    // ---- dual histogram; per-row 2-way wave-parity privatization
    unsigned int hselA = (unsigned int)(wid & 1) << 8;
    unsigned int hselB = 512u + ((unsigned int)(wid & 1) << 8);
    #pragma unroll
    for (int l = 0; l < 8; ++l) {
        int binA = 255, binB = 255;
        if (valid[l]) {
            float keyA = __uint_as_float(kbA[l]);
            binA = (int)((keyA - loA) * scaleA);
            binA = min(max(binA, 0), 255);
            atomicAdd(&hist[hselA + binA], 1u);
            float keyB = __uint_as_float(kbB[l]);
            binB = (int)((keyB - loB) * scaleB);
            binB = min(max(binB, 0), 255);
            atomicAdd(&hist[hselB + binB], 1u);
        }
        binsA[l] = binA; binsB[l] = binB;
    }
    __syncthreads();

    // ---- dual inclusive prefix scan over 256 bins; boundary bin per row
    int hA = (int)(hist[tid] + hist[tid + 256]);
    int hB = (int)(hist[tid + 512] + hist[tid + 768]);
    int inclA = hA, inclB = hB;
    #pragma unroll
    for (int dd = 1; dd < 64; dd <<= 1) {
        int uA = __shfl_up(inclA, dd);
        int uB = __shfl_up(inclB, dd);
        if (lane >= dd) { inclA += uA; inclB += uB; }
    }
    if (lane == 63) { waveSumA[wid] = inclA; waveSumB[wid] = inclB; }
    __syncthreads();
    int offA = 0, offB = 0;
    for (int w = 0; w < wid; ++w) { offA += waveSumA[w]; offB += waveSumB[w]; }
    int cumA = inclA + offA, cumB = inclB + offB;
    if (cumA >= 32 && (cumA - hA) < 32) { sh_b[0] = tid; sh_nless[0] = cumA - hA; }
    if (cumB >= 32 && (cumB - hB) < 32) { sh_b[1] = tid; sh_nless[1] = cumB - hB; }
    __syncthreads();

    int bA = sh_b[0], reqA = 32 - sh_nless[0];
    int bB = sh_b[1], reqB = 32 - sh_nless[1];

    // ---- collect both rows (bins from registers)
    #pragma unroll
    for (int l = 0; l < 8; ++l) {
        if (valid[l]) {
            int j = tid + 256 * l;
            int binA = binsA[l];
            if (binA < bA) {
                int p = atomicAdd(&sh_sel[0], 1);
                topkA[p] = j;
            } else if (binA == bA) {
                int e = atomicAdd(&sh_eq[0], 1);
                if (e < 256) { eqIdxA[e] = j; eqKeyA[e] = kbA[l]; }
            }
            int binB = binsB[l];
            if (binB < bB) {
                int p = atomicAdd(&sh_sel[1], 1);
                topkB[p] = j;
            } else if (binB == bB) {
                int e = atomicAdd(&sh_eq[1], 1);
                if (e < 256) { eqIdxB[e] = j; eqKeyB[e] = kbB[l]; }
            }
        }
    }
    if (tid < 128) qsA[tid] = qkv[rA * QKV_W + tid];
    else           qsB[tid - 128] = qkv[rB * QKV_W + (tid - 128)];
    __syncthreads();

    // ---- boundary-bin exact rank, row A then row B
    int eqA = min(sh_eq[0], 256);
    if (tid < eqA) {
        int myIdx = eqIdxA[tid];
        unsigned int myKey = eqKeyA[tid];
        int rank = 0;
        for (int u = 0; u < eqA; ++u) {
            unsigned int ku = eqKeyA[u];
            rank += (ku < myKey || (ku == myKey && eqIdxA[u] < myIdx)) ? 1 : 0;
        }
        if (rank < reqA) {
            int p = atomicAdd(&sh_sel[0], 1);
            topkA[p] = myIdx;
        }
    }
    int eqB = min(sh_eq[1], 256);
    if (tid < eqB) {
        int myIdx = eqIdxB[tid];
        unsigned int myKey = eqKeyB[tid];
        int rank = 0;
        for (int u = 0; u < eqB; ++u) {
            unsigned int ku = eqKeyB[u];
            rank += (ku < myKey || (ku == myKey && eqIdxB[u] < myIdx)) ? 1 : 0;
        }
        if (rank < reqB) {
            int p = atomicAdd(&sh_sel[1], 1);
            topkB[p] = myIdx;
        }
    }
    __syncthreads();

    // ---- scores + softmax, row A then row B: thread = (head hh, slot j)
    {
        int hh = tid >> 5, j = tid & 31;
        const float4* qpA = (const float4*)&qsA[hh * 16];
        int jjA = topkA[j];
        const float4* kpA = (const float4*)&qkv[jjA * QKV_W + 128 + hh * 16];
        float s = 0.f;
        #pragma unroll
        for (int i = 0; i < 4; ++i) {
            float4 kv = kpA[i], qv = qpA[i];
            s += qv.x * kv.x + qv.y * kv.y + qv.z * kv.z + qv.w * kv.w;
        }
        s *= 0.25f;
        float m = s;
        #pragma unroll
        for (int msk = 16; msk >= 1; msk >>= 1) m = fmaxf(m, __shfl_xor(m, msk));
        float p = expf(s - m);
        float su = p;
        #pragma unroll
        for (int msk = 16; msk >= 1; msk >>= 1) su += __shfl_xor(su, msk);
        prA[tid] = p / su;

        const float4* qpB = (const float4*)&qsB[hh * 16];
        int jjB = topkB[j];
        const float4* kpB = (const float4*)&qkv[jjB * QKV_W + 128 + hh * 16];
        float s2 = 0.f;
        #pragma unroll
        for (int i = 0; i < 4; ++i) {
            float4 kv = kpB[i], qv = qpB[i];
            s2 += qv.x * kv.x + qv.y * kv.y + qv.z * kv.z + qv.w * kv.w;
        }
        s2 *= 0.25f;
        float m2 = s2;
        #pragma unroll
        for (int msk = 16; msk >= 1; msk >>= 1) m2 = fmaxf(m2, __shfl_xor(m2, msk));
        float p2 = expf(s2 - m2);
        float su2 = p2;
        #pragma unroll
        for (int msk = 16; msk >= 1; msk >>= 1) su2 += __shfl_xor(su2, msk);
        prB[tid] = p2 / su2;
    }
    __syncthreads();

    // ---- o = probs @ v : half per row (128 threads each, 32 gathers)
    {
        int e = tid & 127;
        int hh = e >> 4;
        if (tid < 128) {
            float acc = 0.f;
            #pragma unroll
            for (int j = 0; j < 32; ++j) {
                int jj = topkA[j];
                acc += prA[hh * 32 + j] * qkv[jj * QKV_W + 256 + e];
            }
            osA[e] = acc;
        } else {
            float acc = 0.f;
            #pragma unroll
            for (int j = 0; j < 32; ++j) {
                int jj = topkB[j];
                acc += prB[hh * 32 + j] * qkv[jj * QKV_W + 256 + e];
            }
            osB[e] = acc;
        }
    }
    __syncthreads();

    // ---- out-projection: halves read IDENTICAL out_wT addresses (L1 hit)
    {
        int e = tid & 127;
        const float* osp = (tid < 128) ? osA : osB;
        int orow = (tid < 128) ? rA : rB;
        float a = 0.f;
        #pragma unroll
        for (int k = 0; k < 128; k += 4) {
            a += osp[k + 0] * out_wT[(k + 0) * 128 + e]
               + osp[k + 1] * out_wT[(k + 1) * 128 + e]
               + osp[k + 2] * out_wT[(k + 2) * 128 + e]
               + osp[k + 3] * out_wT[(k + 3) * 128 + e];
        }
        out[orow * E_DIM + e] = sanitize(a + out_b[e]);
    }
}

// ---------------------------------------------------------------------------
extern "C" void kernel_launch(void* const* d_in, const int* in_sizes, int n_in,
                              void* d_out, int out_size, void* d_ws, size_t ws_size,
                              hipStream_t stream)
{
    const float* x      = (const float*)d_in[0];
    const float* coords = (const float*)d_in[1];
    const float* ps     = (const float*)d_in[2];
    const float* pe_w   = (const float*)d_in[3];
    const float* pe_b   = (const float*)d_in[4];
    const float* pe_g   = (const float*)d_in[5];
    const float* pe_bt  = (const float*)d_in[6];
    const float* in_w   = (const float*)d_in[7];
    const float* in_b   = (const float*)d_in[8];
    const float* out_w  = (const float*)d_in[9];
    const float* out_b  = (const float*)d_in[10];
    float* out = (float*)d_out;

    float* ws    = (float*)d_ws;
    float4* cw   = (float4*)ws;          // 2048 float4 = 8192 floats
    float* qkvb  = ws + 8192;            // 2000*384 = 768000
    float* owT   = ws + 8192 + 768000;   // 128*128 = 16384

    prep_qkv_kernel<<<GEMM_BLOCKS + 16, 256, 0, stream>>>(
        x, coords, ps, pe_w, pe_b, pe_g, pe_bt, in_w, in_b, out_w,
        cw, qkvb, owT);
    attn_proj_kernel<<<N_NODES / 2, 256, 0, stream>>>(cw, qkvb, owT, out_b, out);
}